// Round 4
// baseline (233.611 us; speedup 1.0000x reference)
//
#include <hip/hip_runtime.h>
#include <hip/hip_bf16.h>

#define NPAIR 136
#define NQ 34         // pairs per quarter (136 = 4*34)
#define NOUT 17408    // NQ * 512 threads
#define NBLK 512      // fused grid: 2 blocks per CU, 8 waves each -> 16 waves/CU

using frag8 = __attribute__((ext_vector_type(8))) short;
using f32x4 = __attribute__((ext_vector_type(4))) float;
using i32x4 = __attribute__((ext_vector_type(4))) int;

// Pack two f32 -> bf16x2 by truncation with ONE v_perm_b32.
__device__ inline int pack_bf16(float lo, float hi){
  unsigned a, b;
  __builtin_memcpy(&a, &hi, 4);
  __builtin_memcpy(&b, &lo, 4);
  return (int)__builtin_amdgcn_perm(a, b, 0x07060302u);
}

struct PairTab { int pi[NPAIR]; int pj[NPAIR]; };
constexpr PairTab make_pairs(){
  PairTab t{}; int u = 0;
  for (int i = 0; i < 16; ++i) for (int j = i; j < 16; ++j){ t.pi[u]=i; t.pj[u]=j; ++u; }
  return t;
}
constexpr PairTab PT = make_pairs();

// Accumulate this thread's 34 pair-products for feature f over the 8 clouds in cb.
// cb layout: [cloud 0..7][row 0..15][f 0..127] bf16, byte ^= ((row&7)<<4) swizzle.
template<int H>
__device__ inline void cell_accum(const char* cb, int f, float (&cacc)[NQ]){
#pragma unroll
  for (int c = 0; c < 8; ++c){
    float z[16];
#pragma unroll
    for (int rr = 0; rr < 16; ++rr){
      int byte = ((c*16 + rr)*256 + f*2) ^ ((rr & 7) << 4);
      unsigned short v = *reinterpret_cast<const unsigned short*>(cb + byte);
      unsigned u32 = ((unsigned)v) << 16;
      float zz; __builtin_memcpy(&zz, &u32, 4);
      z[rr] = zz;
    }
#pragma unroll
    for (int u = 0; u < NQ; ++u)      // compile-time pair indices -> all regs
      cacc[u] = fmaf(z[PT.pi[H*NQ+u]], z[PT.pj[H*NQ+u]], cacc[u]);
  }
}

// ---- fused: gene Gram via MFMA + cell Gram from the same loaded data ----
__global__ __launch_bounds__(512, 4) void fused_kernel(const float* __restrict__ X,
                                                       const float* __restrict__ Y,
                                                       float* __restrict__ cell_partials,
                                                       float* __restrict__ gene_part){
  __shared__ char cellbuf[65536];      // double-buffered: 2 x (8 clouds x 16 rows x 128 f bf16)
  __shared__ float diag[8][16];
  __shared__ float gw[8];
  const int t = threadIdx.x;
  const int wave = t >> 6, lane = t & 63;
  const int r = lane & 15;             // row of Z (0-7 = X, 8-15 = Y)
  const int g = lane >> 4;             // k-group
  const int f = t & 127;               // cell feature
  const int h = t >> 7;                // pair-quarter 0..3 (wave-uniform)

  float cacc[NQ];
#pragma unroll
  for (int u = 0; u < NQ; ++u) cacc[u] = 0.f;
  float gene_acc = 0.f;

  const int cbase = blockIdx.x * 32;   // 32 clouds per block: 4 passes x 8 clouds
  for (int pass = 0; pass < 4; ++pass){
    char* cb = cellbuf + (pass & 1)*32768;
    const int b = cbase + pass*8 + wave;          // one cloud per wave
    const float* base = (r < 8) ? X + (size_t)b*4096 + (size_t)r*512
                                : Y + (size_t)b*4096 + (size_t)(r-8)*512;
    const float* p = base + g*8;
    f32x4 acc0 = {0.f,0.f,0.f,0.f}, acc1 = {0.f,0.f,0.f,0.f};
#pragma unroll
    for (int kk = 0; kk < 16; ++kk){
      const float4* q4 = reinterpret_cast<const float4*>(p + kk*32);
      float4 v0 = q4[0];
      float4 v1 = q4[1];
      i32x4 fi;
      fi[0] = pack_bf16(v0.x, v0.y);
      fi[1] = pack_bf16(v0.z, v0.w);
      fi[2] = pack_bf16(v1.x, v1.y);
      fi[3] = pack_bf16(v1.z, v1.w);
      if (kk >= 12){                   // columns 384..511 -> stage for cell
        int byte = ((wave*16 + r)*256 + (kk-12)*64 + g*16) ^ ((r & 7) << 4);
        *reinterpret_cast<i32x4*>(cb + byte) = fi;
      }
      frag8 fr = __builtin_bit_cast(frag8, fi);
      if (kk & 1) acc1 = __builtin_amdgcn_mfma_f32_16x16x32_bf16(fr, fr, acc1, 0, 0, 0);
      else        acc0 = __builtin_amdgcn_mfma_f32_16x16x32_bf16(fr, fr, acc0, 0, 0, 0);
    }
    f32x4 acc = acc0 + acc1;
    // C/D layout: col = lane&15, row = (lane>>4)*4 + q
    int qd = r - g*4;
    if (qd >= 0 && qd < 4) diag[wave][r] = acc[qd];
    __syncthreads();                   // cellbuf + diag ready (only barrier per pass)
    float s = 0.f;
#pragma unroll
    for (int q = 0; q < 4; ++q){
      int row = g*4 + q;
      float sqd = diag[wave][row] + diag[wave][r] - 2.f*acc[q];
      float dist = sqrtf(fmaxf(sqd, 0.f));
      s += (((row < 8) == (r < 8)) ? -dist : dist);
    }
    gene_acc += s;
    if      (h == 0) cell_accum<0>(cb, f, cacc);
    else if (h == 1) cell_accum<1>(cb, f, cacc);
    else if (h == 2) cell_accum<2>(cb, f, cacc);
    else             cell_accum<3>(cb, f, cacc);
    // no trailing barrier: pass p+2's writes to this buffer are ordered by
    // pass p+1's barrier (all threads passed their reads of this buffer first)
  }
  // gene reduction: wave shuffle + cross-wave LDS
#pragma unroll
  for (int off = 32; off > 0; off >>= 1) gene_acc += __shfl_xor(gene_acc, off);
  if (lane == 0) gw[wave] = gene_acc;
  __syncthreads();
  if (t == 0){
    float s = 0.f;
#pragma unroll
    for (int w = 0; w < 8; ++w) s += gw[w];
    gene_part[blockIdx.x] = s * (1.f/128.f);
  }
  // cell partials (coalesced across t)
  float* dst = cell_partials + (size_t)blockIdx.x * NOUT;
#pragma unroll
  for (int u = 0; u < NQ; ++u) dst[u*512 + t] = cacc[u];
}

__global__ __launch_bounds__(256) void reduce1_kernel(const float* __restrict__ partials,
                                                      float* __restrict__ partial2){
  int o = (blockIdx.x % 68)*256 + threadIdx.x;   // 68*256 = NOUT exactly
  int c = blockIdx.x / 68;                       // 8 chunks of 64 blocks
  int p0 = c*64, p1 = p0 + 64;
  float s0=0.f, s1=0.f, s2=0.f, s3=0.f;
  for (int p = p0; p < p1; p += 4){
    s0 += partials[(size_t)(p+0)*NOUT + o];
    s1 += partials[(size_t)(p+1)*NOUT + o];
    s2 += partials[(size_t)(p+2)*NOUT + o];
    s3 += partials[(size_t)(p+3)*NOUT + o];
  }
  partial2[(size_t)c*NOUT + o] = (s0+s1)+(s2+s3);
}

__global__ __launch_bounds__(256) void reduce2_kernel(const float* __restrict__ partial2,
                                                      float* __restrict__ G){
  int o = blockIdx.x*256 + threadIdx.x;          // grid 68
  float s = 0.f;
#pragma unroll
  for (int c = 0; c < 8; ++c) s += partial2[(size_t)c*NOUT + o];
  G[o] = s;
}

__device__ inline float getG(const float* __restrict__ G, int f, int i, int j){
  int a = i < j ? i : j, c = i < j ? j : i;
  int k = a*16 - (a*(a-1))/2 + (c - a);          // linear index of (a,c), a<=c
  int hh = k / NQ;                               // quarter
  int u = k - hh*NQ;
  return G[u*512 + hh*128 + f];
}

__global__ __launch_bounds__(256) void final_kernel(const float* __restrict__ G,
                                                    const float* __restrict__ gene_part,
                                                    int ngp, float* __restrict__ out){
  int t = threadIdx.x;
  float v = 0.f;
  if (t < 128){
    int f = t;
    float d[16];
#pragma unroll
    for (int i = 0; i < 16; ++i) d[i] = getG(G, f, i, i);
    float sum = 0.f;
#pragma unroll
    for (int i = 0; i < 16; ++i){
#pragma unroll
      for (int j = 0; j < 16; ++j){
        float sqd = d[i] + d[j] - 2.f*getG(G, f, i, j);
        float dist = sqrtf(fmaxf(sqd, 0.f));
        sum += (((i < 8) == (j < 8)) ? -dist : dist);
      }
    }
    v = sum * (1.f/128.f) * (1.f/128.f);         // per-feature value / 128 features
  }
  float gp = 0.f;
  for (int idx = t; idx < ngp; idx += 256) gp += gene_part[idx];
  v += gp * (1.f/16384.f);                       // mean over clouds
  __shared__ float red[256];
  red[t] = v;
  __syncthreads();
  for (int s2 = 128; s2 > 0; s2 >>= 1){
    if (t < s2) red[t] += red[t + s2];
    __syncthreads();
  }
  if (t == 0) out[0] = red[0];
}

extern "C" void kernel_launch(void* const* d_in, const int* in_sizes, int n_in,
                              void* d_out, int out_size, void* d_ws, size_t ws_size,
                              hipStream_t stream){
  const float* X = (const float*)d_in[0];
  const float* Y = (const float*)d_in[1];
  float* out = (float*)d_out;

  float* wsf       = (float*)d_ws;
  float* gene_part = wsf;                        // NBLK floats
  float* Gbuf      = wsf + 1024;                 // NOUT floats
  float* partial2  = wsf + 1024 + NOUT;          // 8*NOUT floats
  float* partials  = wsf + 1024 + 9*NOUT;        // NBLK*NOUT floats (~35.6 MB)

  fused_kernel<<<NBLK, 512, 0, stream>>>(X, Y, partials, gene_part);
  reduce1_kernel<<<68*8, 256, 0, stream>>>(partials, partial2);
  reduce2_kernel<<<68, 256, 0, stream>>>(partial2, Gbuf);
  final_kernel<<<1, 256, 0, stream>>>(Gbuf, gene_part, NBLK, out);
}

// Round 5
// 139.639 us; speedup vs baseline: 1.6730x; 1.6730x over previous
//
#include <hip/hip_runtime.h>
#include <hip/hip_bf16.h>

#define NPAIR 136
#define NH 68         // pairs per half (136 = 2*68)
#define NOUT 17408    // NH * 256 threads
#define NBLK 1024     // 4 blocks per CU -> 16 waves/CU with VGPR<=128
#define NCHUNK 16     // reduce1 chunks (NBLK/64)

using frag8 = __attribute__((ext_vector_type(8))) short;
using f32x4 = __attribute__((ext_vector_type(4))) float;
using i32x4 = __attribute__((ext_vector_type(4))) int;

// Pack two f32 -> bf16x2 by truncation with ONE v_perm_b32.
__device__ inline int pack_bf16(float lo, float hi){
  unsigned a, b;
  __builtin_memcpy(&a, &hi, 4);
  __builtin_memcpy(&b, &lo, 4);
  return (int)__builtin_amdgcn_perm(a, b, 0x07060302u);
}

__device__ inline float bf2f(unsigned short v){
  unsigned u32 = ((unsigned)v) << 16;
  float f; __builtin_memcpy(&f, &u32, 4);
  return f;
}

struct PairTab { int pi[NPAIR]; int pj[NPAIR]; };
constexpr PairTab make_pairs(){
  PairTab t{}; int u = 0;
  for (int i = 0; i < 16; ++i) for (int j = i; j < 16; ++j){ t.pi[u]=i; t.pj[u]=j; ++u; }
  return t;
}
constexpr PairTab PT = make_pairs();

// Accumulate this thread's 68 pair-products for feature f over 4 clouds in cb.
// cb layout: [cloud 0..3][row 0..15][f 0..127] bf16, byte ^= ((row&7)<<4) swizzle.
template<int H>
__device__ inline void cell_accum(const char* cb, int f, float (&cacc)[NH]){
#pragma unroll
  for (int c = 0; c < 4; ++c){
    float z[16];
#pragma unroll
    for (int rr = 0; rr < 16; ++rr){
      int byte = ((c*16 + rr)*256 + f*2) ^ ((rr & 7) << 4);
      unsigned short v = *reinterpret_cast<const unsigned short*>(cb + byte);
      z[rr] = bf2f(v);
    }
#pragma unroll
    for (int u = 0; u < NH; ++u)      // compile-time pair indices -> all regs
      cacc[u] = fmaf(z[PT.pi[H*NH+u]], z[PT.pj[H*NH+u]], cacc[u]);
  }
}

// ---- fused: gene Gram via MFMA + cell Gram from the same loaded data ----
__global__ __launch_bounds__(256, 2) void fused_kernel(const float* __restrict__ X,
                                                       const float* __restrict__ Y,
                                                       unsigned short* __restrict__ cell_partials,
                                                       float* __restrict__ gene_part){
  __shared__ char cellbuf[32768];      // double-buffered: 2 x (4 clouds x 16 rows x 128 f bf16)
  __shared__ float diag[4][16];
  __shared__ float gw[4];
  const int t = threadIdx.x;
  const int wave = t >> 6, lane = t & 63;
  const int r = lane & 15;             // row of Z (0-7 = X, 8-15 = Y)
  const int g = lane >> 4;             // k-group
  const int f = t & 127;               // cell feature
  const int h = t >> 7;                // pair-half 0/1 (wave-uniform)

  float cacc[NH];
#pragma unroll
  for (int u = 0; u < NH; ++u) cacc[u] = 0.f;
  float gene_acc = 0.f;

  const int cbase = blockIdx.x * 16;   // 16 clouds per block: 4 passes x 4 clouds
  for (int pass = 0; pass < 4; ++pass){
    char* cb = cellbuf + (pass & 1)*16384;
    const int b = cbase + pass*4 + wave;          // one cloud per wave
    const float* base = (r < 8) ? X + (size_t)b*4096 + (size_t)r*512
                                : Y + (size_t)b*4096 + (size_t)(r-8)*512;
    const float* p = base + g*8;
    f32x4 acc0 = {0.f,0.f,0.f,0.f}, acc1 = {0.f,0.f,0.f,0.f};
#pragma unroll
    for (int kk = 0; kk < 16; ++kk){
      const float4* q4 = reinterpret_cast<const float4*>(p + kk*32);
      float4 v0 = q4[0];
      float4 v1 = q4[1];
      i32x4 fi;
      fi[0] = pack_bf16(v0.x, v0.y);
      fi[1] = pack_bf16(v0.z, v0.w);
      fi[2] = pack_bf16(v1.x, v1.y);
      fi[3] = pack_bf16(v1.z, v1.w);
      if (kk >= 12){                   // columns 384..511 -> stage for cell
        int byte = ((wave*16 + r)*256 + (kk-12)*64 + g*16) ^ ((r & 7) << 4);
        *reinterpret_cast<i32x4*>(cb + byte) = fi;
      }
      frag8 fr = __builtin_bit_cast(frag8, fi);
      if (kk & 1) acc1 = __builtin_amdgcn_mfma_f32_16x16x32_bf16(fr, fr, acc1, 0, 0, 0);
      else        acc0 = __builtin_amdgcn_mfma_f32_16x16x32_bf16(fr, fr, acc0, 0, 0, 0);
    }
    f32x4 acc = acc0 + acc1;
    // C/D layout: col = lane&15, row = (lane>>4)*4 + q; diag is wave-private
    int qd = r - g*4;
    if (qd >= 0 && qd < 4) diag[wave][r] = acc[qd];
    __syncthreads();                   // cellbuf ready (only barrier per pass)
    float s = 0.f;
#pragma unroll
    for (int q = 0; q < 4; ++q){
      int row = g*4 + q;
      float sqd = diag[wave][row] + diag[wave][r] - 2.f*acc[q];
      float dist = sqrtf(fmaxf(sqd, 0.f));
      s += (((row < 8) == (r < 8)) ? -dist : dist);
    }
    gene_acc += s;
    if (h == 0) cell_accum<0>(cb, f, cacc);
    else        cell_accum<1>(cb, f, cacc);
    // no trailing barrier: next pass's barrier orders reuse of this buffer
  }
  // gene reduction: wave shuffle + cross-wave LDS
#pragma unroll
  for (int off = 32; off > 0; off >>= 1) gene_acc += __shfl_xor(gene_acc, off);
  if (lane == 0) gw[wave] = gene_acc;
  __syncthreads();
  if (t == 0) gene_part[blockIdx.x] = (gw[0]+gw[1]+gw[2]+gw[3]) * (1.f/128.f);
  // cell partials in bf16 (coalesced across t)
  unsigned short* dst = cell_partials + (size_t)blockIdx.x * NOUT;
#pragma unroll
  for (int u = 0; u < NH; ++u){
    __hip_bfloat16 bv = __float2bfloat16(cacc[u]);   // RNE
    unsigned short sv; __builtin_memcpy(&sv, &bv, 2);
    dst[u*256 + t] = sv;
  }
}

__global__ __launch_bounds__(256) void reduce1_kernel(const unsigned short* __restrict__ partials,
                                                      float* __restrict__ partial2){
  int o = (blockIdx.x % 68)*256 + threadIdx.x;   // 68*256 = NOUT exactly
  int c = blockIdx.x / 68;                       // NCHUNK chunks of 64 blocks
  int p0 = c*64, p1 = p0 + 64;
  float s0=0.f, s1=0.f, s2=0.f, s3=0.f;
  for (int p = p0; p < p1; p += 4){
    s0 += bf2f(partials[(size_t)(p+0)*NOUT + o]);
    s1 += bf2f(partials[(size_t)(p+1)*NOUT + o]);
    s2 += bf2f(partials[(size_t)(p+2)*NOUT + o]);
    s3 += bf2f(partials[(size_t)(p+3)*NOUT + o]);
  }
  partial2[(size_t)c*NOUT + o] = (s0+s1)+(s2+s3);
}

__global__ __launch_bounds__(256) void reduce2_kernel(const float* __restrict__ partial2,
                                                      float* __restrict__ G){
  int o = blockIdx.x*256 + threadIdx.x;          // grid 68
  float s = 0.f;
#pragma unroll
  for (int c = 0; c < NCHUNK; ++c) s += partial2[(size_t)c*NOUT + o];
  G[o] = s;
}

__device__ inline float getG(const float* __restrict__ G, int f, int i, int j){
  int a = i < j ? i : j, c = i < j ? j : i;
  int k = a*16 - (a*(a-1))/2 + (c - a);          // linear index of (a,c), a<=c
  int hh = (k >= NH) ? 1 : 0;
  int u = k - hh*NH;
  return G[u*256 + hh*128 + f];
}

__global__ __launch_bounds__(256) void final_kernel(const float* __restrict__ G,
                                                    const float* __restrict__ gene_part,
                                                    int ngp, float* __restrict__ out){
  int t = threadIdx.x;
  float v = 0.f;
  if (t < 128){
    int f = t;
    float d[16];
#pragma unroll
    for (int i = 0; i < 16; ++i) d[i] = getG(G, f, i, i);
    float sum = 0.f;
#pragma unroll
    for (int i = 0; i < 16; ++i){
#pragma unroll
      for (int j = 0; j < 16; ++j){
        float sqd = d[i] + d[j] - 2.f*getG(G, f, i, j);
        float dist = sqrtf(fmaxf(sqd, 0.f));
        sum += (((i < 8) == (j < 8)) ? -dist : dist);
      }
    }
    v = sum * (1.f/128.f) * (1.f/128.f);         // per-feature value / 128 features
  }
  float gp = 0.f;
  for (int idx = t; idx < ngp; idx += 256) gp += gene_part[idx];
  v += gp * (1.f/16384.f);                       // mean over clouds
  __shared__ float red[256];
  red[t] = v;
  __syncthreads();
  for (int s2 = 128; s2 > 0; s2 >>= 1){
    if (t < s2) red[t] += red[t + s2];
    __syncthreads();
  }
  if (t == 0) out[0] = red[0];
}

extern "C" void kernel_launch(void* const* d_in, const int* in_sizes, int n_in,
                              void* d_out, int out_size, void* d_ws, size_t ws_size,
                              hipStream_t stream){
  const float* X = (const float*)d_in[0];
  const float* Y = (const float*)d_in[1];
  float* out = (float*)d_out;

  float* wsf       = (float*)d_ws;
  float* gene_part = wsf;                            // NBLK floats
  float* Gbuf      = wsf + NBLK;                     // NOUT floats
  float* partial2  = wsf + NBLK + NOUT;              // NCHUNK*NOUT floats
  unsigned short* partials =
      (unsigned short*)(wsf + NBLK + (1+NCHUNK)*NOUT);  // NBLK*NOUT bf16 (~35.6 MB)

  fused_kernel<<<NBLK, 256, 0, stream>>>(X, Y, partials, gene_part);
  reduce1_kernel<<<68*NCHUNK, 256, 0, stream>>>(partials, partial2);
  reduce2_kernel<<<68, 256, 0, stream>>>(partial2, Gbuf);
  final_kernel<<<1, 256, 0, stream>>>(Gbuf, gene_part, NBLK, out);
}

// Round 6
// 136.489 us; speedup vs baseline: 1.7116x; 1.0231x over previous
//
#include <hip/hip_runtime.h>
#include <hip/hip_bf16.h>

#define NPAIR 136
#define NH 68         // pairs per half (136 = 2*68)
#define NOUT 17408    // NH * 256 threads
#define NBLK 1024     // 4 blocks per CU -> 16 waves/CU with VGPR<=128
#define NCHUNK 16     // reduce1 chunks (NBLK/64)

using frag8 = __attribute__((ext_vector_type(8))) short;
using f32x4 = __attribute__((ext_vector_type(4))) float;
using i32x4 = __attribute__((ext_vector_type(4))) int;

// Pack two f32 -> bf16x2 by truncation with ONE v_perm_b32.
__device__ inline int pack_bf16(float lo, float hi){
  unsigned a, b;
  __builtin_memcpy(&a, &hi, 4);
  __builtin_memcpy(&b, &lo, 4);
  return (int)__builtin_amdgcn_perm(a, b, 0x07060302u);
}

__device__ inline float bf2f(unsigned short v){
  unsigned u32 = ((unsigned)v) << 16;
  float f; __builtin_memcpy(&f, &u32, 4);
  return f;
}

struct PairTab { int pi[NPAIR]; int pj[NPAIR]; };
constexpr PairTab make_pairs(){
  PairTab t{}; int u = 0;
  for (int i = 0; i < 16; ++i) for (int j = i; j < 16; ++j){ t.pi[u]=i; t.pj[u]=j; ++u; }
  return t;
}
constexpr PairTab PT = make_pairs();

// Accumulate this thread's 68 pair-products for feature f over 4 clouds in cb.
// cb layout: [cloud 0..3][row 0..15][f 0..127] bf16, byte ^= ((row&7)<<4) swizzle.
template<int H>
__device__ inline void cell_accum(const char* cb, int f, float (&cacc)[NH]){
#pragma unroll
  for (int c = 0; c < 4; ++c){
    float z[16];
#pragma unroll
    for (int rr = 0; rr < 16; ++rr){
      int byte = ((c*16 + rr)*256 + f*2) ^ ((rr & 7) << 4);
      unsigned short v = *reinterpret_cast<const unsigned short*>(cb + byte);
      z[rr] = bf2f(v);
    }
#pragma unroll
    for (int u = 0; u < NH; ++u)      // compile-time pair indices -> all regs
      cacc[u] = fmaf(z[PT.pi[H*NH+u]], z[PT.pj[H*NH+u]], cacc[u]);
  }
}

// ---- fused: gene Gram via MFMA + cell Gram from the same loaded data ----
// NOTE: no 2nd __launch_bounds__ arg — empirically it CLAMPS waves/EU on this
// toolchain (r3/r5: (256,2)->~20% occ; r4: (512,4)->~43%). Resources here
// (VGPR~124, LDS 33KB) permit 4 blocks/CU = 50%.
__global__ __launch_bounds__(256) void fused_kernel(const float* __restrict__ X,
                                                    const float* __restrict__ Y,
                                                    unsigned short* __restrict__ cell_partials,
                                                    float* __restrict__ gene_part){
  __shared__ char cellbuf[32768];      // double-buffered: 2 x (4 clouds x 16 rows x 128 f bf16)
  __shared__ float diag[4][16];
  __shared__ float gw[4];
  const int t = threadIdx.x;
  const int wave = t >> 6, lane = t & 63;
  const int r = lane & 15;             // row of Z (0-7 = X, 8-15 = Y)
  const int g = lane >> 4;             // k-group
  const int f = t & 127;               // cell feature
  const int h = t >> 7;                // pair-half 0/1 (wave-uniform)

  float cacc[NH];
#pragma unroll
  for (int u = 0; u < NH; ++u) cacc[u] = 0.f;
  float gene_acc = 0.f;

  const int cbase = blockIdx.x * 16;   // 16 clouds per block: 4 passes x 4 clouds
  for (int pass = 0; pass < 4; ++pass){
    char* cb = cellbuf + (pass & 1)*16384;
    const int b = cbase + pass*4 + wave;          // one cloud per wave
    const float* base = (r < 8) ? X + (size_t)b*4096 + (size_t)r*512
                                : Y + (size_t)b*4096 + (size_t)(r-8)*512;
    const float* p = base + g*8;
    f32x4 acc0 = {0.f,0.f,0.f,0.f}, acc1 = {0.f,0.f,0.f,0.f};
#pragma unroll
    for (int kk = 0; kk < 16; ++kk){
      const float4* q4 = reinterpret_cast<const float4*>(p + kk*32);
      float4 v0 = q4[0];
      float4 v1 = q4[1];
      i32x4 fi;
      fi[0] = pack_bf16(v0.x, v0.y);
      fi[1] = pack_bf16(v0.z, v0.w);
      fi[2] = pack_bf16(v1.x, v1.y);
      fi[3] = pack_bf16(v1.z, v1.w);
      if (kk >= 12){                   // columns 384..511 -> stage for cell
        int byte = ((wave*16 + r)*256 + (kk-12)*64 + g*16) ^ ((r & 7) << 4);
        *reinterpret_cast<i32x4*>(cb + byte) = fi;
      }
      frag8 fr = __builtin_bit_cast(frag8, fi);
      if (kk & 1) acc1 = __builtin_amdgcn_mfma_f32_16x16x32_bf16(fr, fr, acc1, 0, 0, 0);
      else        acc0 = __builtin_amdgcn_mfma_f32_16x16x32_bf16(fr, fr, acc0, 0, 0, 0);
    }
    f32x4 acc = acc0 + acc1;
    // C/D layout: col = lane&15, row = (lane>>4)*4 + q; diag is wave-private
    int qd = r - g*4;
    if (qd >= 0 && qd < 4) diag[wave][r] = acc[qd];
    __syncthreads();                   // cellbuf ready (only barrier per pass)
    float s = 0.f;
#pragma unroll
    for (int q = 0; q < 4; ++q){
      int row = g*4 + q;
      float sqd = diag[wave][row] + diag[wave][r] - 2.f*acc[q];
      float dist = sqrtf(fmaxf(sqd, 0.f));
      s += (((row < 8) == (r < 8)) ? -dist : dist);
    }
    gene_acc += s;
    if (h == 0) cell_accum<0>(cb, f, cacc);
    else        cell_accum<1>(cb, f, cacc);
    // no trailing barrier: next pass's barrier orders reuse of this buffer
  }
  // gene reduction: wave shuffle + cross-wave LDS
#pragma unroll
  for (int off = 32; off > 0; off >>= 1) gene_acc += __shfl_xor(gene_acc, off);
  if (lane == 0) gw[wave] = gene_acc;
  __syncthreads();
  if (t == 0) gene_part[blockIdx.x] = (gw[0]+gw[1]+gw[2]+gw[3]) * (1.f/128.f);
  // cell partials in bf16 (coalesced across t)
  unsigned short* dst = cell_partials + (size_t)blockIdx.x * NOUT;
#pragma unroll
  for (int u = 0; u < NH; ++u){
    __hip_bfloat16 bv = __float2bfloat16(cacc[u]);   // RNE
    unsigned short sv; __builtin_memcpy(&sv, &bv, 2);
    dst[u*256 + t] = sv;
  }
}

__global__ __launch_bounds__(256) void reduce1_kernel(const unsigned short* __restrict__ partials,
                                                      float* __restrict__ partial2){
  int o = (blockIdx.x % 68)*256 + threadIdx.x;   // 68*256 = NOUT exactly
  int c = blockIdx.x / 68;                       // NCHUNK chunks of 64 blocks
  int p0 = c*64, p1 = p0 + 64;
  float s0=0.f, s1=0.f, s2=0.f, s3=0.f;
  for (int p = p0; p < p1; p += 4){
    s0 += bf2f(partials[(size_t)(p+0)*NOUT + o]);
    s1 += bf2f(partials[(size_t)(p+1)*NOUT + o]);
    s2 += bf2f(partials[(size_t)(p+2)*NOUT + o]);
    s3 += bf2f(partials[(size_t)(p+3)*NOUT + o]);
  }
  partial2[(size_t)c*NOUT + o] = (s0+s1)+(s2+s3);
}

__global__ __launch_bounds__(256) void reduce2_kernel(const float* __restrict__ partial2,
                                                      float* __restrict__ G){
  int o = blockIdx.x*256 + threadIdx.x;          // grid 68
  float s = 0.f;
#pragma unroll
  for (int c = 0; c < NCHUNK; ++c) s += partial2[(size_t)c*NOUT + o];
  G[o] = s;
}

__device__ inline float getG(const float* __restrict__ G, int f, int i, int j){
  int a = i < j ? i : j, c = i < j ? j : i;
  int k = a*16 - (a*(a-1))/2 + (c - a);          // linear index of (a,c), a<=c
  int hh = (k >= NH) ? 1 : 0;
  int u = k - hh*NH;
  return G[u*256 + hh*128 + f];
}

__global__ __launch_bounds__(256) void final_kernel(const float* __restrict__ G,
                                                    const float* __restrict__ gene_part,
                                                    int ngp, float* __restrict__ out){
  int t = threadIdx.x;
  float v = 0.f;
  if (t < 128){
    int f = t;
    float d[16];
#pragma unroll
    for (int i = 0; i < 16; ++i) d[i] = getG(G, f, i, i);
    float sum = 0.f;
#pragma unroll
    for (int i = 0; i < 16; ++i){
#pragma unroll
      for (int j = 0; j < 16; ++j){
        float sqd = d[i] + d[j] - 2.f*getG(G, f, i, j);
        float dist = sqrtf(fmaxf(sqd, 0.f));
        sum += (((i < 8) == (j < 8)) ? -dist : dist);
      }
    }
    v = sum * (1.f/128.f) * (1.f/128.f);         // per-feature value / 128 features
  }
  float gp = 0.f;
  for (int idx = t; idx < ngp; idx += 256) gp += gene_part[idx];
  v += gp * (1.f/16384.f);                       // mean over clouds
  __shared__ float red[256];
  red[t] = v;
  __syncthreads();
  for (int s2 = 128; s2 > 0; s2 >>= 1){
    if (t < s2) red[t] += red[t + s2];
    __syncthreads();
  }
  if (t == 0) out[0] = red[0];
}

extern "C" void kernel_launch(void* const* d_in, const int* in_sizes, int n_in,
                              void* d_out, int out_size, void* d_ws, size_t ws_size,
                              hipStream_t stream){
  const float* X = (const float*)d_in[0];
  const float* Y = (const float*)d_in[1];
  float* out = (float*)d_out;

  float* wsf       = (float*)d_ws;
  float* gene_part = wsf;                            // NBLK floats
  float* Gbuf      = wsf + NBLK;                     // NOUT floats
  float* partial2  = wsf + NBLK + NOUT;              // NCHUNK*NOUT floats
  unsigned short* partials =
      (unsigned short*)(wsf + NBLK + (1+NCHUNK)*NOUT);  // NBLK*NOUT bf16 (~35.6 MB)

  fused_kernel<<<NBLK, 256, 0, stream>>>(X, Y, partials, gene_part);
  reduce1_kernel<<<68*NCHUNK, 256, 0, stream>>>(partials, partial2);
  reduce2_kernel<<<68, 256, 0, stream>>>(partial2, Gbuf);
  final_kernel<<<1, 256, 0, stream>>>(Gbuf, gene_part, NBLK, out);
}